// Round 1
// baseline (285.034 us; speedup 1.0000x reference)
//
#include <hip/hip_runtime.h>
#include <stdint.h>

typedef __attribute__((ext_vector_type(8))) short short8;
typedef __attribute__((ext_vector_type(4))) float floatx4;

#define AS1 __attribute__((address_space(1)))
#define AS3 __attribute__((address_space(3)))

__device__ __forceinline__ void gld16(const void* g, void* l) {
  __builtin_amdgcn_global_load_lds((AS1 const void*)g, (AS3 void*)l, 16, 0, 0);
}

__device__ __forceinline__ unsigned short f2bf(float f) {
  unsigned int u = __float_as_uint(f);
  return (unsigned short)((u + 0x7fffu + ((u >> 16) & 1u)) >> 16);
}

// ---------------------------------------------------------------------------
// prep: transpose weights to N-major bf16; fold t*w0[576] into bias0.
// wT0[n][tap*64+c] = w0[(c*9+tap)*256+n]   (256 x 576)
// wT{1,2,3}[n][k]  = w{l}[k*256+n]         (256 x 256)
// wT4[n][k]        = n<27 ? w4[k*27+n] : 0 (32 x 256)
// b0p[n] = b0[n] + t * w0[576*256+n]
// ---------------------------------------------------------------------------
__global__ __launch_bounds__(256) void k_prep(
    const float* __restrict__ w0, const float* __restrict__ b0,
    const float* __restrict__ w1, const float* __restrict__ w2,
    const float* __restrict__ w3, const float* __restrict__ w4,
    const float* __restrict__ coord,
    unsigned short* __restrict__ wT0, unsigned short* __restrict__ wT1,
    unsigned short* __restrict__ wT2, unsigned short* __restrict__ wT3,
    unsigned short* __restrict__ wT4, float* __restrict__ b0p) {
  int e = blockIdx.x * 256 + threadIdx.x;
  if (e < 147456) {
    int n = e / 576, kp = e - n * 576;
    int tap = kp >> 6, c = kp & 63;
    wT0[e] = f2bf(w0[(c * 9 + tap) * 256 + n]);
  } else if (e < 147456 + 3 * 65536) {
    int e2 = e - 147456;
    int l = e2 >> 16;
    int r = e2 & 65535;
    int n = r >> 8, k = r & 255;
    const float* w = (l == 0) ? w1 : (l == 1) ? w2 : w3;
    unsigned short* wt = (l == 0) ? wT1 : (l == 1) ? wT2 : wT3;
    wt[r] = f2bf(w[k * 256 + n]);
  } else if (e < 147456 + 3 * 65536 + 8192) {
    int r = e - (147456 + 3 * 65536);
    int n = r >> 8, k = r & 255;
    wT4[r] = (n < 27) ? f2bf(w4[k * 27 + n]) : (unsigned short)0;
  } else if (e < 147456 + 3 * 65536 + 8192 + 256) {
    int n = e - (147456 + 3 * 65536 + 8192);
    b0p[n] = b0[n] + coord[2] * w0[576 * 256 + n];
  }
}

// ---------------------------------------------------------------------------
// featT: X0[p][c] = bf16(feat[b][c][y][x]), p = b*65536 + y*256 + x. Row = 128B.
// ---------------------------------------------------------------------------
__global__ __launch_bounds__(256) void k_featT(const float* __restrict__ feat,
                                               unsigned short* __restrict__ X0) {
  const int p = blockIdx.x * 256 + threadIdx.x;
  const int b = p >> 16;
  const int off = p & 65535;
  const float* src = feat + ((int64_t)b << 22) + off;
  unsigned int tw[32];
#pragma unroll
  for (int c = 0; c < 32; ++c) {
    float lo = src[(int64_t)(2 * c) << 16];
    float hi = src[(int64_t)(2 * c + 1) << 16];
    tw[c] = (unsigned int)f2bf(lo) | ((unsigned int)f2bf(hi) << 16);
  }
  uint4* dst = (uint4*)(X0 + (int64_t)p * 64);
#pragma unroll
  for (int k = 0; k < 8; ++k) {
    uint4 v;
    v.x = tw[4 * k]; v.y = tw[4 * k + 1]; v.z = tw[4 * k + 2]; v.w = tw[4 * k + 3];
    dst[k] = v;
  }
}

// ---------------------------------------------------------------------------
// GEMM core notes (shared by the three GEMM kernels):
//  tile 128(M) x 128(N), BK=64, 256 threads = 4 waves in 2x2 of 64x64.
//  LDS XOR swizzle: slot for (row, chunk) at byte row*128 + ((chunk^(row&7))<<4)
//  -> global_load_lds (lane-linear dst) stages it by having lane s read global
//     chunk (s&7)^((s>>3)&7); frag ds_read_b128 is then bank-conflict-free.
//  MFMA 16x16x32 bf16: A[m=lane&15][k=(lane>>4)*8+j], C/D row=(lane>>4)*4+r.
// ---------------------------------------------------------------------------

// layers 1..3: Out = bf16(sin(30*(A @ W + b))), A,Out: 131072 x 256 bf16
__global__ __launch_bounds__(256, 2) void k_gemm_mid(
    const unsigned short* __restrict__ A, const unsigned short* __restrict__ WT,
    const float* __restrict__ bias, unsigned short* __restrict__ Out) {
  __shared__ alignas(128) char lds[32768];
  char* As = lds;
  char* Bs = lds + 16384;
  const int tid = threadIdx.x;
  const int bid = blockIdx.x;
  const int64_t m0 = (int64_t)(bid >> 1) * 128;
  const int n0 = (bid & 1) * 128;
  const int lane = tid & 63;
  const int lm = lane & 15;
  const int q = lane >> 4;
  const int wv = tid >> 6;
  const int Rm = (wv >> 1) * 64;
  const int Rn = (wv & 1) * 64;

  const int rbase = tid >> 3;                 // 0..31
  const int gch = (tid & 7) ^ (rbase & 7);    // constant across it (32%8==0)
  const char* aptr = (const char*)A + (m0 + rbase) * 512 + gch * 16;
  const char* bptr = (const char*)WT + (int64_t)(n0 + rbase) * 512 + gch * 16;
  char* lbase = lds + (tid & ~63) * 16;       // wave-uniform

  const int coff0 = ((q ^ (lm & 7)) << 4);
  const int coff1 = (((4 + q) ^ (lm & 7)) << 4);
  int aoff[4], boff[4];
#pragma unroll
  for (int i = 0; i < 4; ++i) {
    aoff[i] = (Rm + i * 16 + lm) * 128;
    boff[i] = (Rn + i * 16 + lm) * 128;
  }

  floatx4 zero = {0.0f, 0.0f, 0.0f, 0.0f};
  floatx4 acc[4][4];
#pragma unroll
  for (int i = 0; i < 4; ++i)
#pragma unroll
    for (int j = 0; j < 4; ++j) acc[i][j] = zero;

  for (int sk = 0; sk < 4; ++sk) {
    __syncthreads();
#pragma unroll
    for (int it = 0; it < 4; ++it) {
      gld16(aptr + it * (32 * 512) + sk * 128, lbase + it * 4096);
      gld16(bptr + it * (32 * 512) + sk * 128, lbase + 16384 + it * 4096);
    }
    __syncthreads();
#pragma unroll
    for (int kk = 0; kk < 2; ++kk) {
      const int co = kk ? coff1 : coff0;
      short8 af[4], bf[4];
#pragma unroll
      for (int i = 0; i < 4; ++i) af[i] = *(const short8*)(As + aoff[i] + co);
#pragma unroll
      for (int j = 0; j < 4; ++j) bf[j] = *(const short8*)(Bs + boff[j] + co);
#pragma unroll
      for (int i = 0; i < 4; ++i)
#pragma unroll
        for (int j = 0; j < 4; ++j)
          acc[i][j] = __builtin_amdgcn_mfma_f32_16x16x32_bf16(af[i], bf[j], acc[i][j], 0, 0, 0);
    }
  }

  float bv[4];
#pragma unroll
  for (int j = 0; j < 4; ++j) bv[j] = bias[n0 + Rn + j * 16 + lm];
#pragma unroll
  for (int i = 0; i < 4; ++i) {
#pragma unroll
    for (int j = 0; j < 4; ++j) {
      const int col = n0 + Rn + j * 16 + lm;
#pragma unroll
      for (int r = 0; r < 4; ++r) {
        const int row = Rm + i * 16 + q * 4 + r;
        float h = __sinf(30.0f * (acc[i][j][r] + bv[j]));
        Out[(m0 + row) * 256 + col] = f2bf(h);
      }
    }
  }
}

// layer 0 as implicit 3x3 conv: K-loop over 9 taps of K=64 each.
__global__ __launch_bounds__(256, 2) void k_gemm0(
    const unsigned short* __restrict__ X0, const unsigned short* __restrict__ WT0,
    const float* __restrict__ b0p, unsigned short* __restrict__ Out) {
  __shared__ alignas(128) char lds[32768];
  char* As = lds;
  char* Bs = lds + 16384;
  const int tid = threadIdx.x;
  const int bid = blockIdx.x;
  const int pbase = (bid >> 1) * 128;          // 128 consecutive pixels, one image row
  const int n0 = (bid & 1) * 128;
  const int y = (pbase >> 8) & 255;
  const int x0 = pbase & 255;                  // 0 or 128
  const int lane = tid & 63;
  const int lm = lane & 15;
  const int q = lane >> 4;
  const int wv = tid >> 6;
  const int Rm = (wv >> 1) * 64;
  const int Rn = (wv & 1) * 64;

  const int rbase = tid >> 3;
  const int gch = (tid & 7) ^ (rbase & 7);
  char* lbase = lds + (tid & ~63) * 16;

  const int coff0 = ((q ^ (lm & 7)) << 4);
  const int coff1 = (((4 + q) ^ (lm & 7)) << 4);
  int aoff[4], boff[4];
#pragma unroll
  for (int i = 0; i < 4; ++i) {
    aoff[i] = (Rm + i * 16 + lm) * 128;
    boff[i] = (Rn + i * 16 + lm) * 128;
  }

  floatx4 zero = {0.0f, 0.0f, 0.0f, 0.0f};
  floatx4 acc[4][4];
#pragma unroll
  for (int i = 0; i < 4; ++i)
#pragma unroll
    for (int j = 0; j < 4; ++j) acc[i][j] = zero;

  for (int tap = 0; tap < 9; ++tap) {
    const int dy = tap / 3 - 1;
    const int dx = tap - (tap / 3) * 3 - 1;
    const int yy = y + dy;
    if (yy < 0 || yy > 255) continue;          // block-uniform: tap contributes zeros
    __syncthreads();
#pragma unroll
    for (int it = 0; it < 4; ++it) {
      int prow = pbase + dy * 256 + dx + it * 32 + rbase;
      prow = prow < 0 ? 0 : (prow > 131071 ? 131071 : prow);
      gld16((const char*)X0 + (int64_t)prow * 128 + gch * 16, lbase + it * 4096);
      const int brow = n0 + it * 32 + rbase;
      gld16((const char*)WT0 + (int64_t)brow * 1152 + tap * 128 + gch * 16,
            lbase + 16384 + it * 4096);
    }
    __syncthreads();
    const bool fixlo = (x0 == 0) && (dx == -1);    // pixel x=0 has no left neighbor
    const bool fixhi = (x0 == 128) && (dx == 1);   // pixel x=255 has no right neighbor
    if (fixlo || fixhi) {
      const int fr = fixlo ? 0 : 127;
      if (tid < 32) *(int*)(As + fr * 128 + tid * 4) = 0;
      __syncthreads();
    }
#pragma unroll
    for (int kk = 0; kk < 2; ++kk) {
      const int co = kk ? coff1 : coff0;
      short8 af[4], bf[4];
#pragma unroll
      for (int i = 0; i < 4; ++i) af[i] = *(const short8*)(As + aoff[i] + co);
#pragma unroll
      for (int j = 0; j < 4; ++j) bf[j] = *(const short8*)(Bs + boff[j] + co);
#pragma unroll
      for (int i = 0; i < 4; ++i)
#pragma unroll
        for (int j = 0; j < 4; ++j)
          acc[i][j] = __builtin_amdgcn_mfma_f32_16x16x32_bf16(af[i], bf[j], acc[i][j], 0, 0, 0);
    }
  }

  float bv[4];
#pragma unroll
  for (int j = 0; j < 4; ++j) bv[j] = b0p[n0 + Rn + j * 16 + lm];
  const int64_t m0 = pbase;
#pragma unroll
  for (int i = 0; i < 4; ++i) {
#pragma unroll
    for (int j = 0; j < 4; ++j) {
      const int col = n0 + Rn + j * 16 + lm;
#pragma unroll
      for (int r = 0; r < 4; ++r) {
        const int row = Rm + i * 16 + q * 4 + r;
        float h = __sinf(30.0f * (acc[i][j][r] + bv[j]));
        Out[(m0 + row) * 256 + col] = f2bf(h);
      }
    }
  }
}

// layer 4: pat[p][0..26] = A @ W4 + b4 (fp32 out, row stride 32)
__global__ __launch_bounds__(256, 2) void k_gemm4(
    const unsigned short* __restrict__ A, const unsigned short* __restrict__ WT4,
    const float* __restrict__ b4, float* __restrict__ Out) {
  __shared__ alignas(128) char lds[16384 + 4096];
  char* As = lds;
  char* Bs = lds + 16384;
  const int tid = threadIdx.x;
  const int64_t m0 = (int64_t)blockIdx.x * 128;
  const int lane = tid & 63;
  const int lm = lane & 15;
  const int q = lane >> 4;
  const int wv = tid >> 6;
  const int Rm = wv * 32;                     // each wave: 32 rows x 32 cols

  const int rbase = tid >> 3;                 // 0..31
  const int gch = (tid & 7) ^ (rbase & 7);
  const char* aptr = (const char*)A + (m0 + rbase) * 512 + gch * 16;
  const char* bptr = (const char*)WT4 + rbase * 512 + gch * 16;
  char* albase = lds + (tid & ~63) * 16;
  char* blbase = lds + 16384 + (tid & ~63) * 16;

  const int coff0 = ((q ^ (lm & 7)) << 4);
  const int coff1 = (((4 + q) ^ (lm & 7)) << 4);
  int aoff[2], boff[2];
#pragma unroll
  for (int i = 0; i < 2; ++i) {
    aoff[i] = (Rm + i * 16 + lm) * 128;
    boff[i] = (i * 16 + lm) * 128;
  }

  floatx4 zero = {0.0f, 0.0f, 0.0f, 0.0f};
  floatx4 acc[2][2];
#pragma unroll
  for (int i = 0; i < 2; ++i)
#pragma unroll
    for (int j = 0; j < 2; ++j) acc[i][j] = zero;

  for (int sk = 0; sk < 4; ++sk) {
    __syncthreads();
#pragma unroll
    for (int it = 0; it < 4; ++it)
      gld16(aptr + it * (32 * 512) + sk * 128, albase + it * 4096);
    gld16(bptr + sk * 128, blbase);
    __syncthreads();
#pragma unroll
    for (int kk = 0; kk < 2; ++kk) {
      const int co = kk ? coff1 : coff0;
      short8 af[2], bf[2];
#pragma unroll
      for (int i = 0; i < 2; ++i) af[i] = *(const short8*)(As + aoff[i] + co);
#pragma unroll
      for (int j = 0; j < 2; ++j) bf[j] = *(const short8*)(Bs + boff[j] + co);
#pragma unroll
      for (int i = 0; i < 2; ++i)
#pragma unroll
        for (int j = 0; j < 2; ++j)
          acc[i][j] = __builtin_amdgcn_mfma_f32_16x16x32_bf16(af[i], bf[j], acc[i][j], 0, 0, 0);
    }
  }

#pragma unroll
  for (int j = 0; j < 2; ++j) {
    const int col = j * 16 + lm;
    if (col < 27) {
      const float bb = b4[col];
#pragma unroll
      for (int i = 0; i < 2; ++i)
#pragma unroll
        for (int r = 0; r < 4; ++r) {
          const int row = Rm + i * 16 + q * 4 + r;
          Out[(m0 + row) * 32 + col] = acc[i][j][r] + bb;
        }
    }
  }
}

// fold3: out[b][c][y][x] = sum_{i,j} pat[(b,y+1-i,x+1-j)][c*9+i*3+j]
__global__ __launch_bounds__(256) void k_fold(const float* __restrict__ pat,
                                              float* __restrict__ out) {
  const int e = blockIdx.x * 256 + threadIdx.x;  // < 393216
  const int x = e & 255;
  const int y = (e >> 8) & 255;
  const int bc = e >> 16;
  const int c = bc % 3;
  const int b = bc / 3;
  float s = 0.0f;
#pragma unroll
  for (int i = 0; i < 3; ++i) {
    const int yy = y + 1 - i;
    if (yy < 0 || yy > 255) continue;
#pragma unroll
    for (int j = 0; j < 3; ++j) {
      const int xx = x + 1 - j;
      if (xx < 0 || xx > 255) continue;
      s += pat[(int64_t)((b << 16) + yy * 256 + xx) * 32 + c * 9 + i * 3 + j];
    }
  }
  out[e] = s;
}

extern "C" void kernel_launch(void* const* d_in, const int* in_sizes, int n_in,
                              void* d_out, int out_size, void* d_ws, size_t ws_size,
                              hipStream_t stream) {
  const float* feat  = (const float*)d_in[0];
  const float* coord = (const float*)d_in[1];
  const float* w0 = (const float*)d_in[2];
  const float* b0 = (const float*)d_in[3];
  const float* w1 = (const float*)d_in[4];
  const float* b1 = (const float*)d_in[5];
  const float* w2 = (const float*)d_in[6];
  const float* b2 = (const float*)d_in[7];
  const float* w3 = (const float*)d_in[8];
  const float* b3 = (const float*)d_in[9];
  const float* w4 = (const float*)d_in[10];
  const float* b4 = (const float*)d_in[11];

  char* ws = (char*)d_ws;
  unsigned short* h0  = (unsigned short*)(ws);
  unsigned short* h1  = (unsigned short*)(ws + 67108864);
  unsigned short* X0  = (unsigned short*)(ws + 134217728);  // 16.78 MB, reused as pat
  float*          pat = (float*)(ws + 134217728);
  unsigned short* wT0 = (unsigned short*)(ws + 150994944);
  unsigned short* wT1 = (unsigned short*)(ws + 151289856);
  unsigned short* wT2 = (unsigned short*)(ws + 151420928);
  unsigned short* wT3 = (unsigned short*)(ws + 151552000);
  unsigned short* wT4 = (unsigned short*)(ws + 151683072);
  float*          b0p = (float*)(ws + 151699456);
  float* out = (float*)d_out;

  hipLaunchKernelGGL(k_prep, dim3(1377), dim3(256), 0, stream,
                     w0, b0, w1, w2, w3, w4, coord, wT0, wT1, wT2, wT3, wT4, b0p);
  hipLaunchKernelGGL(k_featT, dim3(512), dim3(256), 0, stream, feat, X0);
  hipLaunchKernelGGL(k_gemm0, dim3(2048), dim3(256), 0, stream, X0, wT0, b0p, h0);
  hipLaunchKernelGGL(k_gemm_mid, dim3(2048), dim3(256), 0, stream, h0, wT1, b1, h1);
  hipLaunchKernelGGL(k_gemm_mid, dim3(2048), dim3(256), 0, stream, h1, wT2, b2, h0);
  hipLaunchKernelGGL(k_gemm_mid, dim3(2048), dim3(256), 0, stream, h0, wT3, b3, h1);
  hipLaunchKernelGGL(k_gemm4, dim3(1024), dim3(256), 0, stream, h1, wT4, b4, pat);
  hipLaunchKernelGGL(k_fold, dim3(1536), dim3(256), 0, stream, pat, out);
}